// Round 15
// baseline (101.894 us; speedup 1.0000x reference)
//
#include <hip/hip_runtime.h>

// WaveletMixing: out = x + IDWT3(scale(DWT3(x))) along N per (b,d) channel.
// x: (B=8, N=4096, D=768) f32.
// Interior (n in [256,3840)): register-streaming dataflow, 256 samples per
//   thread (14 segments x 3 ch-groups x 8 batch = 336 blocks).
//   Residuals carried load->store in a 36-float register delay ring (RR).
//   r15: x is staged through a double-buffered LDS tile. Per superstep each
//   thread issues 4 float4 global loads (16B/lane, coalesced) for step k+1
//   at the TOP of compute k, ds_write_b128 at the end, 1 barrier/step.
//   Load-to-use distance = 1 superstep (~1300 cyc) -> HBM latency covered.
//   __launch_bounds__(256,4) pins VGPR <= 128 (r14 lesson: edge occupancy).
// Edge tiles (n<256, n>=3840): round-5 generic LDS path (proven).

namespace {

constexpr int NT  = 256;
constexpr int N0  = 4096;
constexpr int DCH = 768;
constexpr int TS  = 256;             // interior samples per thread
constexpr int TE  = 256;             // edge tile size
constexpr int G   = 8;               // edge path: channels per block
constexpr int NDG = DCH / G;         // 96
constexpr int L1v = 2051, L2v = 1029, L3v = 518;

constexpr int NSEG = (N0 - 2 * TE) / TS;  // 14 interior segments
constexpr int NINT = 8 * 3 * NSEG;        // 336 interior blocks

// Shared pool: interior double-buffer 2x[16][256] floats (32 KB);
// edge path round-5 layout needs 7776 floats -> both fit in 8192.
constexpr int SP = 972;
constexpr int OX = 0, OA1 = 356, OD1 = 536, OA2 = 716, OD2 = 804,
              OA3 = 892, OD3 = 932, OREC = 716;

// db4 analysis filters ascending (pywt); HI[k] = (-1)^(k+1)*LO[7-k].
__device__ constexpr float LO[8] = {
  -0.010597401784997278f,  0.032883011666982945f,  0.030841381835986965f,
  -0.18703481171888114f,  -0.02798376941698385f,   0.6308807679295904f,
   0.7148465705525415f,    0.23037781330885523f };
__device__ constexpr float HI[8] = {
  -0.23037781330885523f,   0.7148465705525415f,   -0.6308807679295904f,
  -0.02798376941698385f,   0.18703481171888114f,   0.030841381835986965f,
  -0.032883011666982945f, -0.010597401784997278f };
// Address-ascending copies: F[7-k].
__device__ constexpr float LOF[8] = {
   0.23037781330885523f,   0.7148465705525415f,    0.6308807679295904f,
  -0.02798376941698385f,  -0.18703481171888114f,   0.030841381835986965f,
   0.032883011666982945f, -0.010597401784997278f };
__device__ constexpr float HIF[8] = {
  -0.010597401784997278f, -0.032883011666982945f,  0.030841381835986965f,
   0.18703481171888114f,  -0.02798376941698385f,  -0.6308807679295904f,
   0.7148465705525415f,   -0.23037781330885523f };

__device__ __forceinline__ int refl(int g, int n) {
  g = (g < 0) ? (-g - 1) : g;
  return (g >= n) ? (2 * n - 1 - g) : g;
}

// ---------------- streaming interior ----------------
// Array origins (x/coeff index of element 0 rel n0 at superstep base bk8):
//  xa:  bk8 - 54             a1a: bk8/2 - 30             d1a: bk8/2 - 45
//  a2a: bk8/4 - 18           d2a: bk8/4 - 21
//  a3a/d3a: bk8/8 - 9        r2a: bk8/4 - 21             r1a: bk8/2 - 45
//  RR (residual delay ring): bk8 - 90, 36 deep.
struct Streams {
  float xa[22];
  float a1a[14], d1a[29];
  float a2a[10], d2a[13];
  float a3a[5],  d3a[5];
  float r2a[7],  r1a[11];
};

// SMODE: 0 = no stores, 1 = HEAD (store u=1, tau>=1), 2 = FULL, 3 = TAIL
// (store u=0 all + u=1 tau=0). lx = LDS column base for this thread's
// channel in the CURRENT buffer: lx[i*256] = x[bk8-48+i].
template <int SMODE>
__device__ __forceinline__ void superstep(Streams& S, float (&RR)[36],
                                          const float* __restrict__ lx,
                                          float* __restrict__ orow, int bk8,
                                          float wa, float w0, float w1,
                                          float w2) {
  // merge staged stream batch from LDS (2 lanes/bank -> free)
#pragma unroll
  for (int i = 0; i < 16; ++i)
    S.xa[6 + i] = lx[i * 256];

#pragma unroll
  for (int u = 0; u < 2; ++u) {
    // L1 analysis: 4 new a1/d1
#pragma unroll
    for (int j = 0; j < 4; ++j) {
      float slo = 0.f, shi = 0.f;
#pragma unroll
      for (int k = 0; k < 8; ++k) {
        const float v = S.xa[8 * u + 2 * j + k];
        slo = fmaf(LOF[k], v, slo);
        shi = fmaf(HIF[k], v, shi);
      }
      S.a1a[6 + 4 * u + j]  = slo;
      S.d1a[21 + 4 * u + j] = w0 * shi;
    }
    // L2 analysis: 2 new a2/d2
#pragma unroll
    for (int i = 0; i < 2; ++i) {
      float slo = 0.f, shi = 0.f;
#pragma unroll
      for (int k = 0; k < 8; ++k) {
        const float v = S.a1a[4 * u + 2 * i + k];
        slo = fmaf(LOF[k], v, slo);
        shi = fmaf(HIF[k], v, shi);
      }
      S.a2a[6 + 2 * u + i] = slo;
      S.d2a[9 + 2 * u + i] = w1 * shi;
    }
    // L3 analysis: 1 new a3/d3 (wa/w2 folded at production)
    {
      float slo = 0.f, shi = 0.f;
#pragma unroll
      for (int k = 0; k < 8; ++k) {
        const float v = S.a2a[2 * u + k];
        slo = fmaf(LOF[k], v, slo);
        shi = fmaf(HIF[k], v, shi);
      }
      S.a3a[3 + u] = wa * slo;
      S.d3a[3 + u] = w2 * shi;
    }
    // synth L3: 2 new r2 (even output = odd taps, odd output = even taps)
    {
      float e = 0.f, o = 0.f;
#pragma unroll
      for (int m = 0; m < 4; ++m) {
        e = fmaf(LO[2 * m + 1], S.a3a[u + m], e);
        e = fmaf(HI[2 * m + 1], S.d3a[u + m], e);
        o = fmaf(LO[2 * m],     S.a3a[u + m], o);
        o = fmaf(HI[2 * m],     S.d3a[u + m], o);
      }
      S.r2a[3 + 2 * u]     = e;
      S.r2a[3 + 2 * u + 1] = o;
    }
    // synth L2: 4 new r1
#pragma unroll
    for (int h = 0; h < 2; ++h) {
      float e = 0.f, o = 0.f;
#pragma unroll
      for (int m = 0; m < 4; ++m) {
        e = fmaf(LO[2 * m + 1], S.r2a[2 * u + h + m], e);
        e = fmaf(HI[2 * m + 1], S.d2a[2 * u + h + m], e);
        o = fmaf(LO[2 * m],     S.r2a[2 * u + h + m], o);
        o = fmaf(HI[2 * m],     S.d2a[2 * u + h + m], o);
      }
      S.r1a[3 + 4 * u + 2 * h]     = e;
      S.r1a[3 + 4 * u + 2 * h + 1] = o;
    }
    // synth L1 + residual (from ring) + store
    // batch n (rel n0) = bk8 + 8u - 90 + {0..7}; RR index = 8u + 2tau (+1)
    if (SMODE != 0) {
#pragma unroll
      for (int tau = 0; tau < 4; ++tau) {
        bool doSt;
        if (SMODE == 2)      doSt = true;
        else if (SMODE == 1) doSt = (u == 1) && (tau >= 1);
        else                 doSt = (u == 0) || (tau == 0);
        if (doSt) {
          float e = 0.f, o = 0.f;
#pragma unroll
          for (int m = 0; m < 4; ++m) {
            e = fmaf(LO[2 * m + 1], S.r1a[4 * u + tau + m], e);
            e = fmaf(HI[2 * m + 1], S.d1a[4 * u + tau + m], e);
            o = fmaf(LO[2 * m],     S.r1a[4 * u + tau + m], o);
            o = fmaf(HI[2 * m],     S.d1a[4 * u + tau + m], o);
          }
          const long ofs = bk8 + 8 * u - 90 + 2 * tau;
          orow[ofs * DCH]       = e + RR[8 * u + 2 * tau];
          orow[(ofs + 1) * DCH] = o + RR[8 * u + 2 * tau + 1];
        }
      }
    }
  }
  // residual ring advance (BEFORE xa carries; uses current-step xa[0..15]):
  // RR_new[i] = x[(bk8+16)-90+i]
#pragma unroll
  for (int i = 0; i < 20; ++i) RR[i] = RR[i + 16];
#pragma unroll
  for (int i = 0; i < 16; ++i) RR[20 + i] = S.xa[i];
  // carries: tail -> head (static renaming copies)
#pragma unroll
  for (int i = 0; i < 6; ++i)  S.xa[i]  = S.xa[i + 16];
#pragma unroll
  for (int i = 0; i < 6; ++i)  S.a1a[i] = S.a1a[i + 8];
#pragma unroll
  for (int i = 0; i < 21; ++i) S.d1a[i] = S.d1a[i + 8];
#pragma unroll
  for (int i = 0; i < 6; ++i)  S.a2a[i] = S.a2a[i + 4];
#pragma unroll
  for (int i = 0; i < 9; ++i)  S.d2a[i] = S.d2a[i + 4];
#pragma unroll
  for (int i = 0; i < 3; ++i) { S.a3a[i] = S.a3a[i + 2]; S.d3a[i] = S.d3a[i + 2]; }
#pragma unroll
  for (int i = 0; i < 3; ++i)  S.r2a[i] = S.r2a[i + 4];
#pragma unroll
  for (int i = 0; i < 3; ++i)  S.r1a[i] = S.r1a[i + 8];
}

// One staged step: issue 4 float4 loads for step bk8+16 at the top, compute
// the current step from LDS buf[cur], ds_write the staged data to buf[cur^1],
// barrier, flip. Write-after-read safety: buf[cur^1] was last READ one step
// ago, behind a barrier.
template <int SMODE, bool STG>
__device__ __forceinline__ void run_step(Streams& S, float (&RR)[36],
                                         float* __restrict__ pool, int& cur,
                                         int& bk8,
                                         const float* __restrict__ gsb,
                                         float* __restrict__ orow, int tid,
                                         int c4, int pw, float wa, float w0,
                                         float w1, float w2) {
  float4 s0, s1, s2, s3;
  if (STG) {
    const float* g = gsb + (long)(bk8 - 32 + pw) * DCH + c4;
    s0 = *reinterpret_cast<const float4*>(g);
    s1 = *reinterpret_cast<const float4*>(g + (size_t)4 * DCH);
    s2 = *reinterpret_cast<const float4*>(g + (size_t)8 * DCH);
    s3 = *reinterpret_cast<const float4*>(g + (size_t)12 * DCH);
  }
  superstep<SMODE>(S, RR, pool + cur * 4096 + tid, orow, bk8, wa, w0, w1, w2);
  if (STG) {
    float* l = pool + (cur ^ 1) * 4096 + pw * 256 + c4;
    *reinterpret_cast<float4*>(l)              = s0;
    *reinterpret_cast<float4*>(l + 4 * 256)    = s1;
    *reinterpret_cast<float4*>(l + 8 * 256)    = s2;
    *reinterpret_cast<float4*>(l + 12 * 256)   = s3;
    __syncthreads();
  }
  cur ^= 1;
  bk8 += 16;
}

// ---------------- edge (generic, reflecting) scalar phases ----------------

__device__ void analyze_g(const float* __restrict__ in, int Oin,
                          float* __restrict__ oa, float* __restrict__ od,
                          int cnt, int Oout, int lenout, int i2) {
  for (int p = i2; p < cnt; p += 32) {
    const int gp = refl(Oout + p, lenout);
    const int qb = 2 * gp - 6 - Oin;
    float alo = 0.f, ahi = 0.f;
#pragma unroll
    for (int k = 0; k < 8; ++k) {
      const float v = in[qb + k];
      alo = fmaf(LOF[k], v, alo);
      ahi = fmaf(HIF[k], v, ahi);
    }
    oa[p] = alo;
    od[p] = ahi;
  }
}

__device__ void synth_g(const float* __restrict__ ca,
                        const float* __restrict__ cd, int doff,
                        float* __restrict__ o, float sa, float sd, int npair,
                        int i2) {
  for (int t = i2; t < npair; t += 32) {
    float e = 0.f, ed = 0.f, oe = 0.f, od_ = 0.f;
#pragma unroll
    for (int m = 0; m < 4; ++m) {
      e   = fmaf(LO[2 * m + 1], ca[t + m], e);
      ed  = fmaf(HI[2 * m + 1], cd[t + doff + m], ed);
      oe  = fmaf(LO[2 * m],     ca[t + m], oe);
      od_ = fmaf(HI[2 * m],     cd[t + doff + m], od_);
    }
    o[2 * t]     = sa * e  + sd * ed;
    o[2 * t + 1] = sa * oe + sd * od_;
  }
}

} // namespace

__global__ __launch_bounds__(NT, 4) void wavemix_kernel(
    const float* __restrict__ x, const float* __restrict__ wap,
    const float* __restrict__ wdet, float* __restrict__ out) {
  __shared__ float pool[8192];   // 32 KB: interior dbuf 2x[16][256] / edge 7776
  const int blk = blockIdx.x;
  const int tid = threadIdx.x;

  if (blk < NINT) {
    // -------- register-streaming interior, LDS-staged loads --------
    // Bijective XCD swizzle (NINT = 336 = 8*42).
    const int wgs    = (blk & 7) * (NINT >> 3) + (blk >> 3);
    const int si     = wgs % NSEG;          // 0..13
    const int row    = wgs / NSEG;          // 0..23
    const int wgroup = row % 3;
    const int b      = row / 3;
    const int n0     = (si + 1) * TS;       // 256 + si*256, covers [256,3840)
    const int d0     = wgroup * 256;

    const float* __restrict__ gsb = x + ((size_t)b * N0 + n0) * DCH + d0;
    float* __restrict__ orow = out + ((size_t)b * N0 + n0) * DCH + d0 + tid;
    const float wa = wap[d0 + tid];
    const float w0 = wdet[d0 + tid];
    const float w1 = wdet[DCH + d0 + tid];
    const float w2 = wdet[2 * DCH + d0 + tid];

    const int c4 = 4 * (tid & 63);          // staged channel quad
    const int pw = tid >> 6;                // wave id = position offset

    // Refl-free window: x reads span [n0-48, n0+303] ⊂ [208, 3887].
    Streams S = {};
    float RR[36];
#pragma unroll
    for (int i = 0; i < 36; ++i) RR[i] = 0.f;

    // prologue: stage step-0 batch (offsets -48..-33) into buf0
    {
      const float* g = gsb + (long)(-48 + pw) * DCH + c4;
      float* l = pool + pw * 256 + c4;
      *reinterpret_cast<float4*>(l)            = *reinterpret_cast<const float4*>(g);
      *reinterpret_cast<float4*>(l + 4 * 256)  = *reinterpret_cast<const float4*>(g + (size_t)4 * DCH);
      *reinterpret_cast<float4*>(l + 8 * 256)  = *reinterpret_cast<const float4*>(g + (size_t)8 * DCH);
      *reinterpret_cast<float4*>(l + 12 * 256) = *reinterpret_cast<const float4*>(g + (size_t)12 * DCH);
    }
    __syncthreads();

    int cur = 0, bk8 = 0;
    // warm-up: bk8 = 0..64 (no stores)
#pragma unroll 1
    for (int m = 0; m < 5; ++m)
      run_step<0, true>(S, RR, pool, cur, bk8, gsb, orow, tid, c4, pw, wa, w0, w1, w2);
    // HEAD: outputs n0..n0+5
    run_step<1, true>(S, RR, pool, cur, bk8, gsb, orow, tid, c4, pw, wa, w0, w1, w2);
    // FULL: outputs n0+6 .. n0+245
#pragma unroll 1
    for (int m = 0; m < 15; ++m)
      run_step<2, true>(S, RR, pool, cur, bk8, gsb, orow, tid, c4, pw, wa, w0, w1, w2);
    // TAIL: outputs n0+246 .. n0+255 (no staging, no barrier)
    run_step<3, false>(S, RR, pool, cur, bk8, gsb, orow, tid, c4, pw, wa, w0, w1, w2);
  } else {
    // -------- edge tiles (n in [0,256) or [3840,4096)), LDS path --------
    const int e    = blk - NINT;
    const int nt   = (e & 1) ? 15 : 0;
    const int rest = e >> 1;
    const int dg   = rest % NDG;
    const int b    = rest / NDG;
    const int n0   = nt * TE;
    const int d0   = dg * G;

    // load x tile [n0-46 .. n0+305] (reflected), coalesced float4
    {
      const int q  = tid & 1;
      const int pl = tid >> 1;
      for (int p = pl; p < 352; p += 128) {
        const int g = refl(n0 - 46 + p, N0);
        const float4 v = *reinterpret_cast<const float4*>(
            x + ((size_t)b * N0 + g) * DCH + d0 + 4 * q);
        float* dst = pool + (4 * q) * SP + OX + p;
        dst[0]      = v.x;
        dst[SP]     = v.y;
        dst[2 * SP] = v.z;
        dst[3 * SP] = v.w;
      }
    }

    const int c2 = tid >> 5;
    const int i2 = tid & 31;
    float* P = pool + c2 * SP;
    const float wa = wap[d0 + c2];
    const float w2 = wdet[2 * DCH + d0 + c2];
    const float w1 = wdet[1 * DCH + d0 + c2];
    const float w0 = wdet[0 * DCH + d0 + c2];
    __syncthreads();

    analyze_g(P + OX,  n0 - 46,     P + OA1, P + OD1, 172, n0 / 2 - 20, L1v, i2);
    __syncthreads();
    analyze_g(P + OA1, n0 / 2 - 20, P + OA2, P + OD2,  82, n0 / 4 - 6,  L2v, i2);
    __syncthreads();
    analyze_g(P + OA2, n0 / 4 - 6,  P + OA3, P + OD3,  38, n0 / 8,      L3v, i2);
    __syncthreads();
    synth_g(P + OA3, P + OD3, 0, P + OA2, wa,  w2, 35, i2);  // r2 0..69
    __syncthreads();
    synth_g(P + OA2, P + OD2, 6, P + OA1, 1.f, w1, 66, i2);  // r1 0..131
    __syncthreads();
    for (int t = i2; t < 128; t += 32) {                     // final + residual
      const float* pa = P + OA1;
      const float* pd = P + OD1;
      float e2 = 0.f, ed = 0.f, oe = 0.f, od_ = 0.f;
#pragma unroll
      for (int m = 0; m < 4; ++m) {
        e2  = fmaf(LO[2 * m + 1], pa[t + m], e2);
        ed  = fmaf(HI[2 * m + 1], pd[t + 20 + m], ed);
        oe  = fmaf(LO[2 * m],     pa[t + m], oe);
        od_ = fmaf(HI[2 * m],     pd[t + 20 + m], od_);
      }
      (P + OREC)[2 * t]     = e2 + w0 * ed  + (P + OX)[2 * t + 46];
      (P + OREC)[2 * t + 1] = oe + w0 * od_ + (P + OX)[2 * t + 47];
    }
    __syncthreads();

    // coalesced store
    {
      const int c = tid & 7;
      const int j = tid >> 3;
      const float* R = pool + c * SP + OREC;
      float* orow = out + ((size_t)b * N0 + n0) * DCH + d0 + c;
      for (int pos = j; pos < TE; pos += 32)
        orow[(size_t)pos * DCH] = R[pos];
    }
  }
}

extern "C" void kernel_launch(void* const* d_in, const int* in_sizes, int n_in,
                              void* d_out, int out_size, void* d_ws, size_t ws_size,
                              hipStream_t stream) {
  const float* x  = (const float*)d_in[0];
  const float* wa = (const float*)d_in[1];
  const float* wd = (const float*)d_in[2];
  float* out      = (float*)d_out;

  const int grid = NINT + 8 * NDG * 2;   // 336 interior + 1536 edge = 1872
  wavemix_kernel<<<grid, NT, 0, stream>>>(x, wa, wd, out);
}

// Round 16
// 56.845 us; speedup vs baseline: 1.7925x; 1.7925x over previous
//
#include <hip/hip_runtime.h>

// WaveletMixing: out = x + IDWT3(scale(DWT3(x))) along N per (b,d) channel.
// x: (B=8, N=4096, D=768) f32.
// Interior (n in [256,3840)): register-streaming dataflow, 448 samples per
//   thread (8 segments x 3 ch-groups x 8 batch = 192 blocks <= 1/CU).
//   Residuals carried load->store in a 36-float register delay ring (RR).
//   TS=448 amortizes the fixed 90-sample pipeline skew (34 supersteps per
//   448 outputs = 1.21 steps/16-out vs 1.375 at TS=256) and removes the
//   2-blocks-on-one-CU critical path (pole 44 -> 34 supersteps).
// Edge tiles (n<256, n>=3840): round-5 generic LDS path (proven).
// Structure otherwise identical to round 13 (best verified: 53.6 us).

namespace {

constexpr int NT  = 256;
constexpr int N0  = 4096;
constexpr int DCH = 768;
constexpr int TS  = 448;             // interior samples per thread
constexpr int TE  = 256;             // edge tile size
constexpr int G   = 8;               // edge path: channels per block
constexpr int NDG = DCH / G;         // 96
constexpr int L1v = 2051, L2v = 1029, L3v = 518;

constexpr int NSEG = (N0 - 2 * TE) / TS;  // 8 interior segments
constexpr int NINT = 8 * 3 * NSEG;        // 192 interior blocks

// Edge LDS pool (round-5 layout, proven)
constexpr int SP = 972;
constexpr int OX = 0, OA1 = 356, OD1 = 536, OA2 = 716, OD2 = 804,
              OA3 = 892, OD3 = 932, OREC = 716;

// db4 analysis filters ascending (pywt); HI[k] = (-1)^(k+1)*LO[7-k].
__device__ constexpr float LO[8] = {
  -0.010597401784997278f,  0.032883011666982945f,  0.030841381835986965f,
  -0.18703481171888114f,  -0.02798376941698385f,   0.6308807679295904f,
   0.7148465705525415f,    0.23037781330885523f };
__device__ constexpr float HI[8] = {
  -0.23037781330885523f,   0.7148465705525415f,   -0.6308807679295904f,
  -0.02798376941698385f,   0.18703481171888114f,   0.030841381835986965f,
  -0.032883011666982945f, -0.010597401784997278f };
// Address-ascending copies: F[7-k].
__device__ constexpr float LOF[8] = {
   0.23037781330885523f,   0.7148465705525415f,    0.6308807679295904f,
  -0.02798376941698385f,  -0.18703481171888114f,   0.030841381835986965f,
   0.032883011666982945f, -0.010597401784997278f };
__device__ constexpr float HIF[8] = {
  -0.010597401784997278f, -0.032883011666982945f,  0.030841381835986965f,
   0.18703481171888114f,  -0.02798376941698385f,  -0.6308807679295904f,
   0.7148465705525415f,   -0.23037781330885523f };

__device__ __forceinline__ int refl(int g, int n) {
  g = (g < 0) ? (-g - 1) : g;
  return (g >= n) ? (2 * n - 1 - g) : g;
}

// ---------------- streaming interior ----------------
// Array origins (x/coeff index of element 0 rel n0 at superstep base bk8):
//  xa:  bk8 - 54             a1a: bk8/2 - 30             d1a: bk8/2 - 45
//  a2a: bk8/4 - 18           d2a: bk8/4 - 21
//  a3a/d3a: bk8/8 - 9        r2a: bk8/4 - 21             r1a: bk8/2 - 45
//  RR (residual delay ring): bk8 - 90, 36 deep.
struct Streams {
  float xa[22];
  float a1a[14], d1a[29];
  float a2a[10], d2a[13];
  float a3a[5],  d3a[5];
  float r2a[7],  r1a[11];
};

// SMODE: 0 = no stores, 1 = HEAD (store u=1, tau>=1), 2 = FULL, 3 = TAIL
// (store u=0 all + u=1 tau=0).
template <int SMODE>
__device__ __forceinline__ void superstep(Streams& S, float (&RR)[36],
                                          const float* __restrict__ xrow,
                                          float* __restrict__ orow, int bk8,
                                          float wa, float w0, float w1,
                                          float w2) {
  // 16 stream loads (x offsets bk8-48 .. bk8-33 rel n0)
#pragma unroll
  for (int i = 0; i < 16; ++i)
    S.xa[6 + i] = xrow[(long)(bk8 - 48 + i) * DCH];

#pragma unroll
  for (int u = 0; u < 2; ++u) {
    // L1 analysis: 4 new a1/d1
#pragma unroll
    for (int j = 0; j < 4; ++j) {
      float slo = 0.f, shi = 0.f;
#pragma unroll
      for (int k = 0; k < 8; ++k) {
        const float v = S.xa[8 * u + 2 * j + k];
        slo = fmaf(LOF[k], v, slo);
        shi = fmaf(HIF[k], v, shi);
      }
      S.a1a[6 + 4 * u + j]  = slo;
      S.d1a[21 + 4 * u + j] = w0 * shi;
    }
    // L2 analysis: 2 new a2/d2
#pragma unroll
    for (int i = 0; i < 2; ++i) {
      float slo = 0.f, shi = 0.f;
#pragma unroll
      for (int k = 0; k < 8; ++k) {
        const float v = S.a1a[4 * u + 2 * i + k];
        slo = fmaf(LOF[k], v, slo);
        shi = fmaf(HIF[k], v, shi);
      }
      S.a2a[6 + 2 * u + i] = slo;
      S.d2a[9 + 2 * u + i] = w1 * shi;
    }
    // L3 analysis: 1 new a3/d3 (wa/w2 folded at production)
    {
      float slo = 0.f, shi = 0.f;
#pragma unroll
      for (int k = 0; k < 8; ++k) {
        const float v = S.a2a[2 * u + k];
        slo = fmaf(LOF[k], v, slo);
        shi = fmaf(HIF[k], v, shi);
      }
      S.a3a[3 + u] = wa * slo;
      S.d3a[3 + u] = w2 * shi;
    }
    // synth L3: 2 new r2 (even output = odd taps, odd output = even taps)
    {
      float e = 0.f, o = 0.f;
#pragma unroll
      for (int m = 0; m < 4; ++m) {
        e = fmaf(LO[2 * m + 1], S.a3a[u + m], e);
        e = fmaf(HI[2 * m + 1], S.d3a[u + m], e);
        o = fmaf(LO[2 * m],     S.a3a[u + m], o);
        o = fmaf(HI[2 * m],     S.d3a[u + m], o);
      }
      S.r2a[3 + 2 * u]     = e;
      S.r2a[3 + 2 * u + 1] = o;
    }
    // synth L2: 4 new r1
#pragma unroll
    for (int h = 0; h < 2; ++h) {
      float e = 0.f, o = 0.f;
#pragma unroll
      for (int m = 0; m < 4; ++m) {
        e = fmaf(LO[2 * m + 1], S.r2a[2 * u + h + m], e);
        e = fmaf(HI[2 * m + 1], S.d2a[2 * u + h + m], e);
        o = fmaf(LO[2 * m],     S.r2a[2 * u + h + m], o);
        o = fmaf(HI[2 * m],     S.d2a[2 * u + h + m], o);
      }
      S.r1a[3 + 4 * u + 2 * h]     = e;
      S.r1a[3 + 4 * u + 2 * h + 1] = o;
    }
    // synth L1 + residual (from ring) + store
    // batch n (rel n0) = bk8 + 8u - 90 + {0..7}; RR index = 8u + 2tau (+1)
    if (SMODE != 0) {
#pragma unroll
      for (int tau = 0; tau < 4; ++tau) {
        bool doSt;
        if (SMODE == 2)      doSt = true;
        else if (SMODE == 1) doSt = (u == 1) && (tau >= 1);
        else                 doSt = (u == 0) || (tau == 0);
        if (doSt) {
          float e = 0.f, o = 0.f;
#pragma unroll
          for (int m = 0; m < 4; ++m) {
            e = fmaf(LO[2 * m + 1], S.r1a[4 * u + tau + m], e);
            e = fmaf(HI[2 * m + 1], S.d1a[4 * u + tau + m], e);
            o = fmaf(LO[2 * m],     S.r1a[4 * u + tau + m], o);
            o = fmaf(HI[2 * m],     S.d1a[4 * u + tau + m], o);
          }
          const long ofs = bk8 + 8 * u - 90 + 2 * tau;
          orow[ofs * DCH]       = e + RR[8 * u + 2 * tau];
          orow[(ofs + 1) * DCH] = o + RR[8 * u + 2 * tau + 1];
        }
      }
    }
  }
  // residual ring advance (BEFORE xa carries; uses current-step xa[0..15]):
  // RR_new[i] = x[(bk8+16)-90+i]
#pragma unroll
  for (int i = 0; i < 20; ++i) RR[i] = RR[i + 16];
#pragma unroll
  for (int i = 0; i < 16; ++i) RR[20 + i] = S.xa[i];
  // carries: tail -> head (static renaming copies)
#pragma unroll
  for (int i = 0; i < 6; ++i)  S.xa[i]  = S.xa[i + 16];
#pragma unroll
  for (int i = 0; i < 6; ++i)  S.a1a[i] = S.a1a[i + 8];
#pragma unroll
  for (int i = 0; i < 21; ++i) S.d1a[i] = S.d1a[i + 8];
#pragma unroll
  for (int i = 0; i < 6; ++i)  S.a2a[i] = S.a2a[i + 4];
#pragma unroll
  for (int i = 0; i < 9; ++i)  S.d2a[i] = S.d2a[i + 4];
#pragma unroll
  for (int i = 0; i < 3; ++i) { S.a3a[i] = S.a3a[i + 2]; S.d3a[i] = S.d3a[i + 2]; }
#pragma unroll
  for (int i = 0; i < 3; ++i)  S.r2a[i] = S.r2a[i + 4];
#pragma unroll
  for (int i = 0; i < 3; ++i)  S.r1a[i] = S.r1a[i + 8];
}

// ---------------- edge (generic, reflecting) scalar phases ----------------

__device__ void analyze_g(const float* __restrict__ in, int Oin,
                          float* __restrict__ oa, float* __restrict__ od,
                          int cnt, int Oout, int lenout, int i2) {
  for (int p = i2; p < cnt; p += 32) {
    const int gp = refl(Oout + p, lenout);
    const int qb = 2 * gp - 6 - Oin;
    float alo = 0.f, ahi = 0.f;
#pragma unroll
    for (int k = 0; k < 8; ++k) {
      const float v = in[qb + k];
      alo = fmaf(LOF[k], v, alo);
      ahi = fmaf(HIF[k], v, ahi);
    }
    oa[p] = alo;
    od[p] = ahi;
  }
}

__device__ void synth_g(const float* __restrict__ ca,
                        const float* __restrict__ cd, int doff,
                        float* __restrict__ o, float sa, float sd, int npair,
                        int i2) {
  for (int t = i2; t < npair; t += 32) {
    float e = 0.f, ed = 0.f, oe = 0.f, od_ = 0.f;
#pragma unroll
    for (int m = 0; m < 4; ++m) {
      e   = fmaf(LO[2 * m + 1], ca[t + m], e);
      ed  = fmaf(HI[2 * m + 1], cd[t + doff + m], ed);
      oe  = fmaf(LO[2 * m],     ca[t + m], oe);
      od_ = fmaf(HI[2 * m],     cd[t + doff + m], od_);
    }
    o[2 * t]     = sa * e  + sd * ed;
    o[2 * t + 1] = sa * oe + sd * od_;
  }
}

} // namespace

__global__ __launch_bounds__(NT) void wavemix_kernel(
    const float* __restrict__ x, const float* __restrict__ wap,
    const float* __restrict__ wdet, float* __restrict__ out) {
  __shared__ float pool[G * SP];   // 31104 B (edge path only)
  const int blk = blockIdx.x;
  const int tid = threadIdx.x;

  if (blk < NINT) {
    // -------- register-streaming interior --------
    // Bijective XCD swizzle (NINT = 192 = 8*24); contiguous wgs per XCD =
    // complete (b, ch-group) rows of 8 consecutive segments -> halo
    // re-reads hit that XCD's L2. 192 blocks <= 1 per CU.
    const int wgs    = (blk & 7) * (NINT >> 3) + (blk >> 3);
    const int si     = wgs % NSEG;          // 0..7
    const int row    = wgs / NSEG;          // 0..23
    const int wgroup = row % 3;
    const int b      = row / 3;
    const int n0     = TE + si * TS;        // 256 + si*448, covers [256,3840)
    const int d      = wgroup * 256 + tid;

    const float* __restrict__ xrow = x   + ((size_t)b * N0 + n0) * DCH + d;
    float* __restrict__       orow = out + ((size_t)b * N0 + n0) * DCH + d;
    const float wa = wap[d];
    const float w0 = wdet[d];
    const float w1 = wdet[DCH + d];
    const float w2 = wdet[2 * DCH + d];

    // Refl-free window: x reads span [n0-48, n0+495] ⊂ [208, 3887].
    Streams S = {};
    float RR[36];
#pragma unroll
    for (int i = 0; i < 36; ++i) RR[i] = 0.f;

    int bk8 = 0;
    // warm-up: bk8 = 0..64 (no stores; ring primes itself from the stream)
#pragma unroll 1
    for (int m = 0; m < 5; ++m) {
      superstep<0>(S, RR, xrow, orow, bk8, wa, w0, w1, w2);
      bk8 += 16;
    }
    // HEAD: outputs n0..n0+5
    superstep<1>(S, RR, xrow, orow, bk8, wa, w0, w1, w2);
    bk8 += 16;
    // FULL: outputs n0+6 .. n0+437
#pragma unroll 1
    for (int m = 0; m < 27; ++m) {
      superstep<2>(S, RR, xrow, orow, bk8, wa, w0, w1, w2);
      bk8 += 16;
    }
    // TAIL: outputs n0+438 .. n0+447
    superstep<3>(S, RR, xrow, orow, bk8, wa, w0, w1, w2);
  } else {
    // -------- edge tiles (n in [0,256) or [3840,4096)), LDS path --------
    const int e    = blk - NINT;
    const int nt   = (e & 1) ? 15 : 0;
    const int rest = e >> 1;
    const int dg   = rest % NDG;
    const int b    = rest / NDG;
    const int n0   = nt * TE;
    const int d0   = dg * G;

    // load x tile [n0-46 .. n0+305] (reflected), coalesced float4
    {
      const int q  = tid & 1;
      const int pl = tid >> 1;
      for (int p = pl; p < 352; p += 128) {
        const int g = refl(n0 - 46 + p, N0);
        const float4 v = *reinterpret_cast<const float4*>(
            x + ((size_t)b * N0 + g) * DCH + d0 + 4 * q);
        float* dst = pool + (4 * q) * SP + OX + p;
        dst[0]      = v.x;
        dst[SP]     = v.y;
        dst[2 * SP] = v.z;
        dst[3 * SP] = v.w;
      }
    }

    const int c2 = tid >> 5;
    const int i2 = tid & 31;
    float* P = pool + c2 * SP;
    const float wa = wap[d0 + c2];
    const float w2 = wdet[2 * DCH + d0 + c2];
    const float w1 = wdet[1 * DCH + d0 + c2];
    const float w0 = wdet[0 * DCH + d0 + c2];
    __syncthreads();

    analyze_g(P + OX,  n0 - 46,     P + OA1, P + OD1, 172, n0 / 2 - 20, L1v, i2);
    __syncthreads();
    analyze_g(P + OA1, n0 / 2 - 20, P + OA2, P + OD2,  82, n0 / 4 - 6,  L2v, i2);
    __syncthreads();
    analyze_g(P + OA2, n0 / 4 - 6,  P + OA3, P + OD3,  38, n0 / 8,      L3v, i2);
    __syncthreads();
    synth_g(P + OA3, P + OD3, 0, P + OA2, wa,  w2, 35, i2);  // r2 0..69
    __syncthreads();
    synth_g(P + OA2, P + OD2, 6, P + OA1, 1.f, w1, 66, i2);  // r1 0..131
    __syncthreads();
    for (int t = i2; t < 128; t += 32) {                     // final + residual
      const float* pa = P + OA1;
      const float* pd = P + OD1;
      float e2 = 0.f, ed = 0.f, oe = 0.f, od_ = 0.f;
#pragma unroll
      for (int m = 0; m < 4; ++m) {
        e2  = fmaf(LO[2 * m + 1], pa[t + m], e2);
        ed  = fmaf(HI[2 * m + 1], pd[t + 20 + m], ed);
        oe  = fmaf(LO[2 * m],     pa[t + m], oe);
        od_ = fmaf(HI[2 * m],     pd[t + 20 + m], od_);
      }
      (P + OREC)[2 * t]     = e2 + w0 * ed  + (P + OX)[2 * t + 46];
      (P + OREC)[2 * t + 1] = oe + w0 * od_ + (P + OX)[2 * t + 47];
    }
    __syncthreads();

    // coalesced store
    {
      const int c = tid & 7;
      const int j = tid >> 3;
      const float* R = pool + c * SP + OREC;
      float* orow = out + ((size_t)b * N0 + n0) * DCH + d0 + c;
      for (int pos = j; pos < TE; pos += 32)
        orow[(size_t)pos * DCH] = R[pos];
    }
  }
}

extern "C" void kernel_launch(void* const* d_in, const int* in_sizes, int n_in,
                              void* d_out, int out_size, void* d_ws, size_t ws_size,
                              hipStream_t stream) {
  const float* x  = (const float*)d_in[0];
  const float* wa = (const float*)d_in[1];
  const float* wd = (const float*)d_in[2];
  float* out      = (float*)d_out;

  const int grid = NINT + 8 * NDG * 2;   // 192 interior + 1536 edge = 1728
  wavemix_kernel<<<grid, NT, 0, stream>>>(x, wa, wd, out);
}

// Round 17
// 53.046 us; speedup vs baseline: 1.9209x; 1.0716x over previous
//
#include <hip/hip_runtime.h>

// WaveletMixing: out = x + IDWT3(scale(DWT3(x))) along N per (b,d) channel.
// x: (B=8, N=4096, D=768) f32.
// Interior (n in [256,3840)): register-streaming dataflow, 256 samples per
//   thread (14 segments x 3 ch-groups x 8 batch = 336 blocks). Residuals
//   carried load->store in a 36-float register delay ring (RR).
//   r17: dead-phase elimination at pipeline boundaries -- warmup/drain
//   supersteps skip productions whose outputs are provably never consumed
//   (liveness verified per ring slot). ~12% fewer interior VALU ops, zero
//   structural/register change vs round 13 (best verified: 53.6 us).
// Edge tiles (n<256, n>=3840): round-5 generic LDS path (proven).

namespace {

constexpr int NT  = 256;
constexpr int N0  = 4096;
constexpr int DCH = 768;
constexpr int TS  = 256;             // interior samples per thread
constexpr int TE  = 256;             // edge tile size
constexpr int G   = 8;               // edge path: channels per block
constexpr int NDG = DCH / G;         // 96
constexpr int L1v = 2051, L2v = 1029, L3v = 518;

constexpr int NSEG = (N0 - 2 * TE) / TS;  // 14 interior segments
constexpr int NINT = 8 * 3 * NSEG;        // 336 interior blocks

// Edge LDS pool (round-5 layout, proven)
constexpr int SP = 972;
constexpr int OX = 0, OA1 = 356, OD1 = 536, OA2 = 716, OD2 = 804,
              OA3 = 892, OD3 = 932, OREC = 716;

// db4 analysis filters ascending (pywt); HI[k] = (-1)^(k+1)*LO[7-k].
__device__ constexpr float LO[8] = {
  -0.010597401784997278f,  0.032883011666982945f,  0.030841381835986965f,
  -0.18703481171888114f,  -0.02798376941698385f,   0.6308807679295904f,
   0.7148465705525415f,    0.23037781330885523f };
__device__ constexpr float HI[8] = {
  -0.23037781330885523f,   0.7148465705525415f,   -0.6308807679295904f,
  -0.02798376941698385f,   0.18703481171888114f,   0.030841381835986965f,
  -0.032883011666982945f, -0.010597401784997278f };
// Address-ascending copies: F[7-k].
__device__ constexpr float LOF[8] = {
   0.23037781330885523f,   0.7148465705525415f,    0.6308807679295904f,
  -0.02798376941698385f,  -0.18703481171888114f,   0.030841381835986965f,
   0.032883011666982945f, -0.010597401784997278f };
__device__ constexpr float HIF[8] = {
  -0.010597401784997278f, -0.032883011666982945f,  0.030841381835986965f,
   0.18703481171888114f,  -0.02798376941698385f,  -0.6308807679295904f,
   0.7148465705525415f,   -0.23037781330885523f };

__device__ __forceinline__ int refl(int g, int n) {
  g = (g < 0) ? (-g - 1) : g;
  return (g >= n) ? (2 * n - 1 - g) : g;
}

// ---------------- streaming interior ----------------
// Array origins (x/coeff index of element 0 rel n0 at superstep base bk8):
//  xa:  bk8 - 54             a1a: bk8/2 - 30             d1a: bk8/2 - 45
//  a2a: bk8/4 - 18           d2a: bk8/4 - 21
//  a3a/d3a: bk8/8 - 9        r2a: bk8/4 - 21             r1a: bk8/2 - 45
//  RR (residual delay ring): bk8 - 90, 36 deep.
// Production coverage per step (rel n0-scaled):  a1/d1: bk8/2+[-24,-17]
//  a2/d2: bk8/4+[-12,-9]   a3/d3: bk8/8+[-6,-5]   r2: bk8/4+[-18,-15]
//  r1: bk8/2+[-42,-35]
// Consumption ranges: a1 in [-18,151], d1 [0,130], a2 [-6,75], d2 [0,68],
//  a3/d3 [0,37], r2 [0,68], r1 [0,130]  ->  liveness per bk8 drives the
//  template flags below.
struct Streams {
  float xa[22];
  float a1a[14], d1a[29];
  float a2a[10], d2a[13];
  float a3a[5],  d3a[5];
  float r2a[7],  r1a[11];
};

// SMODE: 0 = no stores, 1 = HEAD (store u=1, tau>=1), 2 = FULL, 3 = TAIL
// (store u=0 all + u=1 tau=0). P* flags gate productions that are dead at
// pipeline boundaries (all skipped values verified never-consumed).
template <int SMODE, bool PD1, bool PA2, bool PD2, bool PA3, bool PR2,
          bool PR1>
__device__ __forceinline__ void superstep(Streams& S, float (&RR)[36],
                                          const float* __restrict__ xrow,
                                          float* __restrict__ orow, int bk8,
                                          float wa, float w0, float w1,
                                          float w2) {
  // 16 stream loads (x offsets bk8-48 .. bk8-33 rel n0)
#pragma unroll
  for (int i = 0; i < 16; ++i)
    S.xa[6 + i] = xrow[(long)(bk8 - 48 + i) * DCH];

#pragma unroll
  for (int u = 0; u < 2; ++u) {
    // L1 analysis: 4 new a1 (+d1 if live)
#pragma unroll
    for (int j = 0; j < 4; ++j) {
      float slo = 0.f, shi = 0.f;
#pragma unroll
      for (int k = 0; k < 8; ++k) {
        const float v = S.xa[8 * u + 2 * j + k];
        slo = fmaf(LOF[k], v, slo);
        if (PD1) shi = fmaf(HIF[k], v, shi);
      }
      S.a1a[6 + 4 * u + j] = slo;
      if (PD1) S.d1a[21 + 4 * u + j] = w0 * shi;
    }
    // L2 analysis: 2 new a2 (+d2 if live)
    if (PA2) {
#pragma unroll
      for (int i = 0; i < 2; ++i) {
        float slo = 0.f, shi = 0.f;
#pragma unroll
        for (int k = 0; k < 8; ++k) {
          const float v = S.a1a[4 * u + 2 * i + k];
          slo = fmaf(LOF[k], v, slo);
          if (PD2) shi = fmaf(HIF[k], v, shi);
        }
        S.a2a[6 + 2 * u + i] = slo;
        if (PD2) S.d2a[9 + 2 * u + i] = w1 * shi;
      }
    }
    // L3 analysis: 1 new a3/d3 (wa/w2 folded at production)
    if (PA3) {
      float slo = 0.f, shi = 0.f;
#pragma unroll
      for (int k = 0; k < 8; ++k) {
        const float v = S.a2a[2 * u + k];
        slo = fmaf(LOF[k], v, slo);
        shi = fmaf(HIF[k], v, shi);
      }
      S.a3a[3 + u] = wa * slo;
      S.d3a[3 + u] = w2 * shi;
    }
    // synth L3: 2 new r2 (even output = odd taps, odd output = even taps)
    if (PR2) {
      float e = 0.f, o = 0.f;
#pragma unroll
      for (int m = 0; m < 4; ++m) {
        e = fmaf(LO[2 * m + 1], S.a3a[u + m], e);
        e = fmaf(HI[2 * m + 1], S.d3a[u + m], e);
        o = fmaf(LO[2 * m],     S.a3a[u + m], o);
        o = fmaf(HI[2 * m],     S.d3a[u + m], o);
      }
      S.r2a[3 + 2 * u]     = e;
      S.r2a[3 + 2 * u + 1] = o;
    }
    // synth L2: 4 new r1
    if (PR1) {
#pragma unroll
      for (int h = 0; h < 2; ++h) {
        float e = 0.f, o = 0.f;
#pragma unroll
        for (int m = 0; m < 4; ++m) {
          e = fmaf(LO[2 * m + 1], S.r2a[2 * u + h + m], e);
          e = fmaf(HI[2 * m + 1], S.d2a[2 * u + h + m], e);
          o = fmaf(LO[2 * m],     S.r2a[2 * u + h + m], o);
          o = fmaf(HI[2 * m],     S.d2a[2 * u + h + m], o);
        }
        S.r1a[3 + 4 * u + 2 * h]     = e;
        S.r1a[3 + 4 * u + 2 * h + 1] = o;
      }
    }
    // synth L1 + residual (from ring) + store
    // batch n (rel n0) = bk8 + 8u - 90 + {0..7}; RR index = 8u + 2tau (+1)
    if (SMODE != 0) {
#pragma unroll
      for (int tau = 0; tau < 4; ++tau) {
        bool doSt;
        if (SMODE == 2)      doSt = true;
        else if (SMODE == 1) doSt = (u == 1) && (tau >= 1);
        else                 doSt = (u == 0) || (tau == 0);
        if (doSt) {
          float e = 0.f, o = 0.f;
#pragma unroll
          for (int m = 0; m < 4; ++m) {
            e = fmaf(LO[2 * m + 1], S.r1a[4 * u + tau + m], e);
            e = fmaf(HI[2 * m + 1], S.d1a[4 * u + tau + m], e);
            o = fmaf(LO[2 * m],     S.r1a[4 * u + tau + m], o);
            o = fmaf(HI[2 * m],     S.d1a[4 * u + tau + m], o);
          }
          const long ofs = bk8 + 8 * u - 90 + 2 * tau;
          orow[ofs * DCH]       = e + RR[8 * u + 2 * tau];
          orow[(ofs + 1) * DCH] = o + RR[8 * u + 2 * tau + 1];
        }
      }
    }
  }
  // residual ring advance (BEFORE xa carries; uses current-step xa[0..15]):
  // RR_new[i] = x[(bk8+16)-90+i]
#pragma unroll
  for (int i = 0; i < 20; ++i) RR[i] = RR[i + 16];
#pragma unroll
  for (int i = 0; i < 16; ++i) RR[20 + i] = S.xa[i];
  // carries: tail -> head (static renaming copies; stale values harmless --
  // they feed only dead productions per the liveness table)
#pragma unroll
  for (int i = 0; i < 6; ++i)  S.xa[i]  = S.xa[i + 16];
#pragma unroll
  for (int i = 0; i < 6; ++i)  S.a1a[i] = S.a1a[i + 8];
#pragma unroll
  for (int i = 0; i < 21; ++i) S.d1a[i] = S.d1a[i + 8];
#pragma unroll
  for (int i = 0; i < 6; ++i)  S.a2a[i] = S.a2a[i + 4];
#pragma unroll
  for (int i = 0; i < 9; ++i)  S.d2a[i] = S.d2a[i + 4];
#pragma unroll
  for (int i = 0; i < 3; ++i) { S.a3a[i] = S.a3a[i + 2]; S.d3a[i] = S.d3a[i + 2]; }
#pragma unroll
  for (int i = 0; i < 3; ++i)  S.r2a[i] = S.r2a[i + 4];
#pragma unroll
  for (int i = 0; i < 3; ++i)  S.r1a[i] = S.r1a[i + 8];
}

// ---------------- edge (generic, reflecting) scalar phases ----------------

__device__ void analyze_g(const float* __restrict__ in, int Oin,
                          float* __restrict__ oa, float* __restrict__ od,
                          int cnt, int Oout, int lenout, int i2) {
  for (int p = i2; p < cnt; p += 32) {
    const int gp = refl(Oout + p, lenout);
    const int qb = 2 * gp - 6 - Oin;
    float alo = 0.f, ahi = 0.f;
#pragma unroll
    for (int k = 0; k < 8; ++k) {
      const float v = in[qb + k];
      alo = fmaf(LOF[k], v, alo);
      ahi = fmaf(HIF[k], v, ahi);
    }
    oa[p] = alo;
    od[p] = ahi;
  }
}

__device__ void synth_g(const float* __restrict__ ca,
                        const float* __restrict__ cd, int doff,
                        float* __restrict__ o, float sa, float sd, int npair,
                        int i2) {
  for (int t = i2; t < npair; t += 32) {
    float e = 0.f, ed = 0.f, oe = 0.f, od_ = 0.f;
#pragma unroll
    for (int m = 0; m < 4; ++m) {
      e   = fmaf(LO[2 * m + 1], ca[t + m], e);
      ed  = fmaf(HI[2 * m + 1], cd[t + doff + m], ed);
      oe  = fmaf(LO[2 * m],     ca[t + m], oe);
      od_ = fmaf(HI[2 * m],     cd[t + doff + m], od_);
    }
    o[2 * t]     = sa * e  + sd * ed;
    o[2 * t + 1] = sa * oe + sd * od_;
  }
}

} // namespace

__global__ __launch_bounds__(NT) void wavemix_kernel(
    const float* __restrict__ x, const float* __restrict__ wap,
    const float* __restrict__ wdet, float* __restrict__ out) {
  __shared__ float pool[G * SP];   // 31104 B (edge path only)
  const int blk = blockIdx.x;
  const int tid = threadIdx.x;

  if (blk < NINT) {
    // -------- register-streaming interior --------
    // Bijective XCD swizzle (NINT = 336 = 8*42); contiguous wgs per XCD =
    // 3 complete (b, ch-group) rows of 14 consecutive segments -> halo
    // re-reads hit that XCD's L2.
    const int wgs    = (blk & 7) * (NINT >> 3) + (blk >> 3);
    const int si     = wgs % NSEG;          // 0..13
    const int row    = wgs / NSEG;          // 0..23
    const int wgroup = row % 3;
    const int b      = row / 3;
    const int n0     = (si + 1) * TS;       // 256 + si*256, covers [256,3840)
    const int d      = wgroup * 256 + tid;

    const float* __restrict__ xrow = x   + ((size_t)b * N0 + n0) * DCH + d;
    float* __restrict__       orow = out + ((size_t)b * N0 + n0) * DCH + d;
    const float wa = wap[d];
    const float w0 = wdet[d];
    const float w1 = wdet[DCH + d];
    const float w2 = wdet[2 * DCH + d];

    // Refl-free window: x reads span [n0-48, n0+303] ⊂ [208, 3887].
    Streams S = {};
    float RR[36];
#pragma unroll
    for (int i = 0; i < 36; ++i) RR[i] = 0.f;

    // Warmup with dead-phase skips (liveness thresholds: d1 live bk8>=34,
    // a2>=12, d2>=36, a3>=40, r2>=60, r1>=70; drain: d1 dead bk8>=310,
    // d2 dead bk8>=324).
    //            SMODE  PD1    PA2    PD2    PA3    PR2    PR1
    superstep<0, false, false, false, false, false, false>(S, RR, xrow, orow, 0,   wa, w0, w1, w2);
    superstep<0, false, true,  false, false, false, false>(S, RR, xrow, orow, 16,  wa, w0, w1, w2);
    superstep<0, false, true,  false, false, false, false>(S, RR, xrow, orow, 32,  wa, w0, w1, w2);
    superstep<0, true,  true,  true,  true,  false, false>(S, RR, xrow, orow, 48,  wa, w0, w1, w2);
    superstep<0, true,  true,  true,  true,  true,  false>(S, RR, xrow, orow, 64,  wa, w0, w1, w2);
    // HEAD: outputs n0..n0+5
    superstep<1, true,  true,  true,  true,  true,  true >(S, RR, xrow, orow, 80,  wa, w0, w1, w2);
    // FULL: outputs n0+6 .. n0+229 (bk8 = 96..304)
    int bk8 = 96;
#pragma unroll 1
    for (int m = 0; m < 14; ++m) {
      superstep<2, true, true, true, true, true, true>(S, RR, xrow, orow, bk8, wa, w0, w1, w2);
      bk8 += 16;
    }
    // FULL drain: outputs n0+230 .. n0+245 (d1 production dead)
    superstep<2, false, true,  true,  true,  true,  true >(S, RR, xrow, orow, 320, wa, w0, w1, w2);
    // TAIL: outputs n0+246 .. n0+255 (d1, d2 dead)
    superstep<3, false, true,  false, true,  true,  true >(S, RR, xrow, orow, 336, wa, w0, w1, w2);
  } else {
    // -------- edge tiles (n in [0,256) or [3840,4096)), LDS path --------
    const int e    = blk - NINT;
    const int nt   = (e & 1) ? 15 : 0;
    const int rest = e >> 1;
    const int dg   = rest % NDG;
    const int b    = rest / NDG;
    const int n0   = nt * TE;
    const int d0   = dg * G;

    // load x tile [n0-46 .. n0+305] (reflected), coalesced float4
    {
      const int q  = tid & 1;
      const int pl = tid >> 1;
      for (int p = pl; p < 352; p += 128) {
        const int g = refl(n0 - 46 + p, N0);
        const float4 v = *reinterpret_cast<const float4*>(
            x + ((size_t)b * N0 + g) * DCH + d0 + 4 * q);
        float* dst = pool + (4 * q) * SP + OX + p;
        dst[0]      = v.x;
        dst[SP]     = v.y;
        dst[2 * SP] = v.z;
        dst[3 * SP] = v.w;
      }
    }

    const int c2 = tid >> 5;
    const int i2 = tid & 31;
    float* P = pool + c2 * SP;
    const float wa = wap[d0 + c2];
    const float w2 = wdet[2 * DCH + d0 + c2];
    const float w1 = wdet[1 * DCH + d0 + c2];
    const float w0 = wdet[0 * DCH + d0 + c2];
    __syncthreads();

    analyze_g(P + OX,  n0 - 46,     P + OA1, P + OD1, 172, n0 / 2 - 20, L1v, i2);
    __syncthreads();
    analyze_g(P + OA1, n0 / 2 - 20, P + OA2, P + OD2,  82, n0 / 4 - 6,  L2v, i2);
    __syncthreads();
    analyze_g(P + OA2, n0 / 4 - 6,  P + OA3, P + OD3,  38, n0 / 8,      L3v, i2);
    __syncthreads();
    synth_g(P + OA3, P + OD3, 0, P + OA2, wa,  w2, 35, i2);  // r2 0..69
    __syncthreads();
    synth_g(P + OA2, P + OD2, 6, P + OA1, 1.f, w1, 66, i2);  // r1 0..131
    __syncthreads();
    for (int t = i2; t < 128; t += 32) {                     // final + residual
      const float* pa = P + OA1;
      const float* pd = P + OD1;
      float e2 = 0.f, ed = 0.f, oe = 0.f, od_ = 0.f;
#pragma unroll
      for (int m = 0; m < 4; ++m) {
        e2  = fmaf(LO[2 * m + 1], pa[t + m], e2);
        ed  = fmaf(HI[2 * m + 1], pd[t + 20 + m], ed);
        oe  = fmaf(LO[2 * m],     pa[t + m], oe);
        od_ = fmaf(HI[2 * m],     pd[t + 20 + m], od_);
      }
      (P + OREC)[2 * t]     = e2 + w0 * ed  + (P + OX)[2 * t + 46];
      (P + OREC)[2 * t + 1] = oe + w0 * od_ + (P + OX)[2 * t + 47];
    }
    __syncthreads();

    // coalesced store
    {
      const int c = tid & 7;
      const int j = tid >> 3;
      const float* R = pool + c * SP + OREC;
      float* orow = out + ((size_t)b * N0 + n0) * DCH + d0 + c;
      for (int pos = j; pos < TE; pos += 32)
        orow[(size_t)pos * DCH] = R[pos];
    }
  }
}

extern "C" void kernel_launch(void* const* d_in, const int* in_sizes, int n_in,
                              void* d_out, int out_size, void* d_ws, size_t ws_size,
                              hipStream_t stream) {
  const float* x  = (const float*)d_in[0];
  const float* wa = (const float*)d_in[1];
  const float* wd = (const float*)d_in[2];
  float* out      = (float*)d_out;

  const int grid = NINT + 8 * NDG * 2;   // 336 interior + 1536 edge = 1872
  wavemix_kernel<<<grid, NT, 0, stream>>>(x, wa, wd, out);
}